// Round 1
// baseline (157.599 us; speedup 1.0000x reference)
//
#include <hip/hip_runtime.h>
#include <hip/hip_fp16.h>

// NeuronToSpatialGrid: out[b,e,p] = (sum_n exp(-||c_p - x_n||^2/S2) * F[b,n,e]) / (sum_n exp(...) + EPS)
// B=4, N=4096, E=256, P=64*64=4096.  Fused GEMM with on-the-fly A (weights) + row-norm epilogue.

typedef __attribute__((ext_vector_type(8))) _Float16 half8;
typedef __attribute__((ext_vector_type(4))) float floatx4;

#define NB 4
#define NN 4096
#define NE 256
#define NP 4096

// ---------- kernel 1: features [B][N][E] f32 -> FT [B][E][N] f16 (transposed for k-contiguous B frags)
__global__ __launch_bounds__(256) void feat_transpose(const float* __restrict__ in,
                                                      __half* __restrict__ ft) {
    __shared__ float tile[32][33];
    const int b  = blockIdx.z;
    const int n0 = blockIdx.x * 32;
    const int e0 = blockIdx.y * 32;
    const int tx = threadIdx.x, ty = threadIdx.y;
#pragma unroll
    for (int i = ty; i < 32; i += 8)
        tile[i][tx] = in[(size_t)(b * NN + n0 + i) * NE + e0 + tx];
    __syncthreads();
#pragma unroll
    for (int i = ty; i < 32; i += 8)
        ft[(size_t)(b * NE + e0 + i) * NN + n0 + tx] = __float2half_rn(tile[tx][i]);
}

// ---------- kernel 2: fused weight-gen + GEMM + row-normalize
// grid = 256 blocks (1/CU), 512 threads (8 waves, 2/SIMD).
// Block tile: BM=64 grid-points x BE=256 (all E) x BK=32 per step, K=4096.
__global__ __launch_bounds__(512, 2) void nw_gemm(const __half* __restrict__ FT,   // [B][E][N]
                                                  const float* __restrict__ pos,   // [B][N][2]
                                                  float* __restrict__ out) {      // [B][E][P]
    __shared__ float2 pos_s[NN];          // 32 KB: all positions for this batch
    __shared__ __half A_s[64][40];        // 5 KB: weight tile, pad 32->40 halves (80B = 20 banks, 2-way = free)
    __shared__ __half Bt_s[256][40];      // 20 KB: feature tile [e][k], same padding
    __shared__ float S_s[64];             // 1/(rowsum+eps)

    const int bid = blockIdx.x;
    const int xcd = bid & 7;              // XCD-aware: each XCD streams one batch's 2MB FT -> L2-resident
    const int b   = xcd >> 1;
    const int mt  = (bid >> 3) + ((xcd & 1) << 5);   // 0..63
    const int m0  = mt * 64;
    const int tid = threadIdx.x;

    // --- load all positions for batch b into LDS (once) ---
    const float2* pg = (const float2*)(pos + (size_t)b * NN * 2);
    for (int i = tid; i < NN; i += 512) pos_s[i] = pg[i];

    // --- A-gen mapping: thread t -> k-pair kp=t&15 (k = ks+2kp,+1), rows r0=(t>>4)*2, r0+1 ---
    const int kp = tid & 15;
    const int r0 = (tid >> 4) * 2;
    const int p0 = m0 + r0;               // p0 even -> both rows share gx (never crosses %64 boundary)
    const float gxv = (float)(p0 >> 6) * (1.0f / 63.0f);
    const float gy0 = (float)(p0 & 63) * (1.0f / 63.0f);
    const float gy1 = gy0 + (1.0f / 63.0f);

    // --- B staging mapping: thread t -> e-row t>>1, k-half (t&1)*16 (32B per thread) ---
    const int brow = tid >> 1;
    const int bh   = tid & 1;
    const __half* bsrc = FT + ((size_t)b * NE + brow) * NN + bh * 16;

    // --- wave/fragment mapping: 8 waves as 2(m) x 4(n), wave tile 32x64 ---
    const int wave = tid >> 6, lane = tid & 63;
    const int m_w = (wave >> 2) * 32;
    const int n_w = (wave & 3) * 64;
    const int fr = lane & 15, quad = lane >> 4;

    floatx4 acc[2][4] = {};
    float sum0 = 0.f, sum1 = 0.f;

    __syncthreads();   // pos_s ready

    for (int ks = 0; ks < NN; ks += 32) {
        // issue global loads early (latency hidden behind W-gen VALU)
        uint4 bv0 = *(const uint4*)(bsrc + ks);
        uint4 bv1 = *(const uint4*)(bsrc + ks + 8);

        // generate 4 weights (2 k x 2 rows); dx^2 reused across the 2 rows
        float2 q0 = pos_s[ks + kp * 2];
        float2 q1 = pos_s[ks + kp * 2 + 1];
        float dx0 = gxv - q0.x, dx1 = gxv - q1.x;
        float dxs0 = dx0 * dx0, dxs1 = dx1 * dx1;
        float dy00 = gy0 - q0.y, dy01 = gy0 - q1.y;
        float dy10 = gy1 - q0.y, dy11 = gy1 - q1.y;
        float w00 = __expf((dxs0 + dy00 * dy00) * -50.0f);   // -1/SIGMA2 = -50
        float w01 = __expf((dxs1 + dy01 * dy01) * -50.0f);
        float w10 = __expf((dxs0 + dy10 * dy10) * -50.0f);
        float w11 = __expf((dxs1 + dy11 * dy11) * -50.0f);
        sum0 += w00 + w01;
        sum1 += w10 + w11;

        __syncthreads();   // previous iteration's fragment reads complete

        *(uint4*)(&Bt_s[brow][bh * 16])     = bv0;
        *(uint4*)(&Bt_s[brow][bh * 16 + 8]) = bv1;
        *(__half2*)(&A_s[r0][kp * 2])     = __floats2half2_rn(w00, w01);
        *(__half2*)(&A_s[r0 + 1][kp * 2]) = __floats2half2_rn(w10, w11);

        __syncthreads();   // tiles ready

        // fragment reads: row*80B + quad*16B, 16B-aligned, 2-way bank aliasing (free)
        half8 af0 = *(const half8*)(&A_s[m_w + fr][quad * 8]);
        half8 af1 = *(const half8*)(&A_s[m_w + 16 + fr][quad * 8]);
        half8 bf0 = *(const half8*)(&Bt_s[n_w + fr][quad * 8]);
        half8 bf1 = *(const half8*)(&Bt_s[n_w + 16 + fr][quad * 8]);
        half8 bf2 = *(const half8*)(&Bt_s[n_w + 32 + fr][quad * 8]);
        half8 bf3 = *(const half8*)(&Bt_s[n_w + 48 + fr][quad * 8]);

        acc[0][0] = __builtin_amdgcn_mfma_f32_16x16x32_f16(af0, bf0, acc[0][0], 0, 0, 0);
        acc[0][1] = __builtin_amdgcn_mfma_f32_16x16x32_f16(af0, bf1, acc[0][1], 0, 0, 0);
        acc[0][2] = __builtin_amdgcn_mfma_f32_16x16x32_f16(af0, bf2, acc[0][2], 0, 0, 0);
        acc[0][3] = __builtin_amdgcn_mfma_f32_16x16x32_f16(af0, bf3, acc[0][3], 0, 0, 0);
        acc[1][0] = __builtin_amdgcn_mfma_f32_16x16x32_f16(af1, bf0, acc[1][0], 0, 0, 0);
        acc[1][1] = __builtin_amdgcn_mfma_f32_16x16x32_f16(af1, bf1, acc[1][1], 0, 0, 0);
        acc[1][2] = __builtin_amdgcn_mfma_f32_16x16x32_f16(af1, bf2, acc[1][2], 0, 0, 0);
        acc[1][3] = __builtin_amdgcn_mfma_f32_16x16x32_f16(af1, bf3, acc[1][3], 0, 0, 0);
    }

    // --- row-sum reduce: 16 threads (kp=0..15) share rows r0,r0+1; butterfly within 16-lane groups ---
#pragma unroll
    for (int off = 1; off < 16; off <<= 1) {
        sum0 += __shfl_xor(sum0, off, 64);
        sum1 += __shfl_xor(sum1, off, 64);
    }
    if (kp == 0) {
        S_s[r0]     = 1.0f / (sum0 + 1e-8f);
        S_s[r0 + 1] = 1.0f / (sum1 + 1e-8f);
    }
    __syncthreads();

    // --- epilogue: scale by 1/(S+eps), store dwordx4 along p (64B coalesced segments) ---
    float* outb = out + (size_t)b * NE * NP;
#pragma unroll
    for (int i = 0; i < 2; i++) {
        const int rbase = m_w + i * 16 + quad * 4;
        floatx4 sv = *(const floatx4*)(&S_s[rbase]);   // broadcast within 16-lane groups
        const int pbase = m0 + rbase;
#pragma unroll
        for (int j = 0; j < 4; j++) {
            const int e = n_w + j * 16 + fr;
            floatx4 o = acc[i][j];
            o.x *= sv.x; o.y *= sv.y; o.z *= sv.z; o.w *= sv.w;
            *(floatx4*)(&outb[(size_t)e * NP + pbase]) = o;
        }
    }
}

extern "C" void kernel_launch(void* const* d_in, const int* in_sizes, int n_in,
                              void* d_out, int out_size, void* d_ws, size_t ws_size,
                              hipStream_t stream) {
    const float* feat = (const float*)d_in[0];   // [4][4096][256] f32
    const float* pos  = (const float*)d_in[1];   // [4][4096][2]  f32
    float* out = (float*)d_out;                  // [4][256][4096] f32
    __half* FT = (__half*)d_ws;                  // needs 4*256*4096*2 = 8.4 MB scratch

    hipLaunchKernelGGL(feat_transpose, dim3(NN / 32, NE / 32, NB), dim3(32, 8), 0, stream,
                       feat, FT);
    hipLaunchKernelGGL(nw_gemm, dim3(NB * (NP / 64)), dim3(512), 0, stream,
                       FT, pos, out);
}